// Round 7
// baseline (794.547 us; speedup 1.0000x reference)
//
#include <hip/hip_runtime.h>
#include <hip/hip_cooperative_groups.h>

namespace cg = cooperative_groups;

// ---------------------------------------------------------------------------
// MolNet layer, round 7: 3 dispatches total.
//   1) fused_pre_k (cooperative, 512 blocks):
//        phase0: zero dc | xbuild X/R2-vec | weight packs + Ai/Aj + RBF LUT
//        phase1: packed 64-bit degree/cnt atomics  +  node MFMA GEMM (overlap)
//        phase2: counting-sort scan (block-redundant base sums) + dis
//        phase3: scatter edges into col-sorted SE
//   2) edge_sorted_k (unchanged from round 6)
//   3) gemm_sv_k (unchanged from round 6)
// ---------------------------------------------------------------------------

typedef __attribute__((ext_vector_type(8))) short bf16x8;
typedef __attribute__((ext_vector_type(4))) float f32x4;
#define MFMA16(a, b, c) __builtin_amdgcn_mfma_f32_16x16x32_bf16(a, b, c, 0, 0, 0)

__device__ __forceinline__ unsigned short f2bf(float x) {
    union { float f; unsigned u; } v; v.f = x;
    unsigned r = v.u + 0x7FFF + ((v.u >> 16) & 1);
    return (unsigned short)(r >> 16);
}
__device__ __forceinline__ float bf2f(unsigned short h) {
    union { unsigned u; float f; } v; v.u = ((unsigned)h) << 16; return v.f;
}
__device__ __forceinline__ float ulo(unsigned u) {
    union { unsigned u; float f; } v; v.u = u << 16; return v.f;
}
__device__ __forceinline__ float uhi(unsigned u) {
    union { unsigned u; float f; } v; v.u = u & 0xffff0000u; return v.f;
}
__device__ __forceinline__ float silu_f(float x) {
    return x * __builtin_amdgcn_rcpf(1.0f + __expf(-x));
}
__device__ __forceinline__ float tanh_f(float x) {
    return 1.0f - 2.0f * __builtin_amdgcn_rcpf(1.0f + __expf(2.0f * x));
}
__device__ __forceinline__ int rfl(int x) { return __builtin_amdgcn_readfirstlane(x); }

// ---------------- fused pre-pipeline ---------------------------------------
struct PreArgs {
    const int* ei; const float* attr;
    const float* scalar; const float* vec;
    const float* Ws2s; const float* Ws2v; const float* Wv2s;
    const float* Wsl; const float* Wvl; const float* Wv2v;
    const float* bs2s; const float* bs2v; const float* bv2s;
    unsigned long long* dc;         // [N] packed: lo32 = fx(sum attr), hi32 = cnt
    int* offA; int* offB; float* dis;
    unsigned short* X; unsigned short* R2;
    unsigned short* BT6; unsigned short* BTs; unsigned short* BTv;
    float* T2; int2* SE;
    unsigned short* PC3;
    int N, E;
};

__device__ void phase0_f(const PreArgs& a, int tid, int nth) {
    // zero dc
    for (int i = tid; i < a.N; i += nth) a.dc[i] = 0ULL;
    // xbuild
    for (int idx = tid; idx < a.N * 64; idx += nth) {
        int n = idx >> 6, c = idx & 63;
        float v0 = a.vec[(size_t)n * 192 + c];
        float v1 = a.vec[(size_t)n * 192 + 64 + c];
        float v2 = a.vec[(size_t)n * 192 + 128 + c];
        a.X[(size_t)n * 128 + c] = f2bf(a.scalar[(size_t)n * 64 + c]);
        a.X[(size_t)n * 128 + 64 + c] = f2bf(sqrtf(v0 * v0 + v1 * v1 + v2 * v2));
        unsigned short* rw = a.R2 + (size_t)n * 384 + c * 6;
        rw[3] = f2bf(v0);
        *(unsigned*)(rw + 4) = (unsigned)f2bf(v1) | ((unsigned)f2bf(v2) << 16);
    }
    // weight prep + RBF table
    const int PREP = 24576 + 8192 + 4096 + 8192 + 513 * 64;
    for (int idx = tid; idx < PREP; idx += nth) {
        if (idx < 24576) {
            int y = idx >> 12, n = (idx >> 6) & 63, k = idx & 63;
            const float* W = (y < 2) ? a.Ws2s : (y < 4) ? a.Ws2v : a.Wv2s;
            int kk = (y & 1) ? (64 + k) : k;
            a.BT6[idx] = f2bf(W[kk * 64 + n]);
        } else if (idx < 32768) {
            int j = idx - 24576;
            int n = j >> 7, k = j & 127;
            a.BTs[(size_t)n * 128 + k] = f2bf(a.Wsl[k * 64 + n]);
        } else if (idx < 36864) {
            int j = idx - 32768;
            int n = j >> 6, k = j & 63;
            a.BTv[(size_t)n * 192 + k] = f2bf(a.Wvl[(64 + k) * 64 + n]);
        } else if (idx < 45056) {
            int j = idx - 36864;
            int half = j >> 12;         // 0: Aj (row side), 1: Ai (col side)
            int k = (j >> 6) & 63, c = j & 63;
            const float* Wr = a.Wv2v + (half ? 0 : 64 * 64) + k * 64;
            float acc = 0.0f;
            for (int m = 0; m < 64; ++m) acc += Wr[m] * a.Wvl[m * 64 + c];
            a.BTv[(size_t)c * 192 + (half ? 128 : 64) + k] = f2bf(acc);
        } else {
            int j = idx - 45056;
            int s = j >> 6, c = j & 63;
            float d = (float)s * (6.0f / 512.0f);
            float acc = 0.0f;
            for (int l = 0; l < 50; ++l) {
                float dl = d - 0.10204081632653061f * (float)l;
                acc += __expf(-48.02f * dl * dl) * a.Wv2s[(128 + l) * 64 + c];
            }
            a.T2[(s * 64 + c) * 2] = acc;
            if (s > 0) a.T2[((s - 1) * 64 + c) * 2 + 1] = acc;
        }
    }
}

__device__ void phase1_f(const PreArgs& a, int tid, int nth) {
    // degree/count: one packed 64-bit atomic per edge
    for (int e = tid; e < a.E; e += nth) {
        int col = a.ei[a.E + e];
        unsigned fx = (unsigned)(a.attr[e] * 1048576.0f + 0.5f);
        atomicAdd(&a.dc[col], (1ULL << 32) | (unsigned long long)fx);
    }
    // node MFMA GEMM (independent of dc) — overlaps with the atomics grid-wide
    const int lane = threadIdx.x & 63;
    const int quad = lane >> 4, l = lane & 15;
    const int wid = tid >> 6, nw = nth >> 6;
    const int mtiles = (a.N + 15) / 16;
    for (int mtile = wid; mtile < mtiles; mtile += nw) {
        const int r0 = mtile * 16;
        const int arow = min(r0 + l, a.N - 1);
        const unsigned short* ap = a.X + (size_t)arow * 128 + quad * 8;
        bf16x8 as0 = *(const bf16x8*)ap;
        bf16x8 as1 = *(const bf16x8*)(ap + 32);
        bf16x8 av0 = *(const bf16x8*)(ap + 64);
        bf16x8 av1 = *(const bf16x8*)(ap + 96);
        f32x4 acc[6][4];
#pragma unroll
        for (int y = 0; y < 6; ++y) {
            bf16x8 a0 = (y < 4) ? as0 : av0;
            bf16x8 a1 = (y < 4) ? as1 : av1;
            const unsigned short* bp = a.BT6 + (size_t)y * 4096 + (size_t)l * 64 + quad * 8;
#pragma unroll
            for (int nt = 0; nt < 4; ++nt) {
                acc[y][nt] = (f32x4){0.f, 0.f, 0.f, 0.f};
                bf16x8 b0 = *(const bf16x8*)(bp + nt * 1024);
                bf16x8 b1 = *(const bf16x8*)(bp + nt * 1024 + 32);
                acc[y][nt] = MFMA16(a0, b0, acc[y][nt]);
                acc[y][nt] = MFMA16(a1, b1, acc[y][nt]);
            }
        }
#pragma unroll
        for (int nt = 0; nt < 4; ++nt) {
            int col = nt * 16 + l;
            float b0 = a.bs2s[col], b1 = a.bs2v[col], b2 = a.bv2s[col];
#pragma unroll
            for (int i = 0; i < 4; ++i) {
                int row = r0 + quad * 4 + i;
                if (row < a.N) {
                    unsigned short* pd = a.PC3 + (size_t)row * 192 + col * 3;
                    pd[0] = f2bf(acc[0][nt][i] + b0);
                    pd[1] = f2bf(acc[2][nt][i] + b1);
                    pd[2] = f2bf(acc[4][nt][i] + b2);
                    unsigned short* rd = a.R2 + (size_t)row * 384 + col * 6;
                    *(unsigned*)rd = (unsigned)f2bf(acc[1][nt][i]) |
                                     ((unsigned)f2bf(acc[3][nt][i]) << 16);
                    rd[2] = f2bf(acc[5][nt][i]);
                }
            }
        }
    }
}

__device__ void phase2_f(const PreArgs& a) {
    const int nch = (a.N + 255) / 256;
    const int b = blockIdx.x;
    if (b >= nch) return;
    __shared__ int sred[256];
    __shared__ int sscan[256];
    const int start = b * 256;
    // base = total cnt of all nodes before this chunk (redundant parallel sum)
    int partial = 0;
    for (int i = threadIdx.x; i < start; i += 256)
        partial += (int)(a.dc[i] >> 32);
    sred[threadIdx.x] = partial;
    __syncthreads();
    for (int s = 128; s > 0; s >>= 1) {
        if (threadIdx.x < s) sred[threadIdx.x] += sred[threadIdx.x + s];
        __syncthreads();
    }
    const int base = sred[0];
    const int i = start + threadIdx.x;
    unsigned long long d = (i < a.N) ? a.dc[i] : 0ULL;
    sscan[threadIdx.x] = (int)(d >> 32);
    __syncthreads();
    for (int s = 1; s < 256; s <<= 1) {
        int t = (threadIdx.x >= s) ? sscan[threadIdx.x - s] : 0;
        __syncthreads();
        sscan[threadIdx.x] += t;
        __syncthreads();
    }
    if (i < a.N) {
        int off = base + sscan[threadIdx.x];
        a.offA[i + 1] = off;
        a.offB[i + 1] = off;
        float deg = (float)(unsigned)(d & 0xffffffffULL) * (1.0f / 1048576.0f);
        a.dis[i] = (deg > 0.0f) ? rsqrtf(deg) : 0.0f;
    }
    if (b == 0 && threadIdx.x == 0) { a.offA[0] = 0; a.offB[0] = 0; }
}

__device__ void phase3_f(const PreArgs& a, int tid, int nth) {
    for (int e = tid; e < a.E; e += nth) {
        int row = a.ei[e];
        int col = a.ei[a.E + e];
        int p = atomicAdd(&a.offA[col], 1);
        a.SE[p] = make_int2(row, __float_as_int(a.dis[row] * a.attr[e]));
    }
}

__global__ __launch_bounds__(256, 2) void fused_pre_k(PreArgs a) {
    cg::grid_group grid = cg::this_grid();
    const int tid = blockIdx.x * 256 + threadIdx.x;
    const int nth = gridDim.x * 256;
    phase0_f(a, tid, nth);
    __threadfence();
    grid.sync();
    phase1_f(a, tid, nth);
    __threadfence();
    grid.sync();
    phase2_f(a);
    __threadfence();
    grid.sync();
    phase3_f(a, tid, nth);
}

// fallback path (plain launches, if cooperative launch is unavailable)
__global__ __launch_bounds__(256) void phase0_k(PreArgs a) {
    phase0_f(a, blockIdx.x * 256 + threadIdx.x, gridDim.x * 256);
}
__global__ __launch_bounds__(256, 2) void phase1_k(PreArgs a) {
    phase1_f(a, blockIdx.x * 256 + threadIdx.x, gridDim.x * 256);
}
__global__ __launch_bounds__(256) void phase2_k(PreArgs a) { phase2_f(a); }
__global__ __launch_bounds__(256) void phase3_k(PreArgs a) {
    phase3_f(a, blockIdx.x * 256 + threadIdx.x, gridDim.x * 256);
}

// ---------------- edge kernel (unchanged from round 6) ---------------------
#define CPW 4
__global__ __launch_bounds__(256) void edge_sorted_k(
    const float* __restrict__ pos, const float* __restrict__ dis,
    const unsigned short* __restrict__ PC3, const unsigned short* __restrict__ R2,
    const float* __restrict__ T2, const int2* __restrict__ SE,
    const int* __restrict__ offB,
    unsigned short* __restrict__ Xs, unsigned short* __restrict__ Xv,
    float* __restrict__ Wsum, int N) {
    const int lane = threadIdx.x & 63;
    const int wave = rfl((blockIdx.x * 256 + threadIdx.x) >> 6);
    const int c0 = wave * CPW;
    const int cend = min(c0 + CPW, N);
    for (int col = c0; col < cend; ++col) {
        const int e0 = rfl(offB[col]);
        const int e1 = rfl(offB[col + 1]);
        const float dcol = dis[col];
        const float px = pos[col * 3], py = pos[col * 3 + 1], pz = pos[col * 3 + 2];
        const unsigned short* pcb = PC3 + (size_t)col * 192 + lane * 3;
        const float pc0 = bf2f(pcb[0]), pc1 = bf2f(pcb[1]), pc2 = bf2f(pcb[2]);
        const unsigned* rc = (const unsigned*)(R2 + (size_t)col * 384 + lane * 6);
        const unsigned cd1 = rc[1], cd2 = rc[2];
        const float wc0 = uhi(cd1), wc1 = ulo(cd2), wc2 = uhi(cd2);
        float a1 = 0, a2 = 0, ws = 0;
        float b30 = 0, b31 = 0, b32 = 0, bv0 = 0, bv1 = 0, bv2 = 0;
        for (int e = e0; e < e1; ++e) {
            const int2 se = SE[e];
            const int row = rfl(se.x);
            const float nrm = dcol * __int_as_float(rfl(se.y));
            const unsigned* rp = (const unsigned*)(R2 + (size_t)row * 384 + lane * 6);
            const unsigned d0 = rp[0], d1 = rp[1], d2 = rp[2];
            const float r0 = px - pos[row * 3 + 0];
            const float r1 = py - pos[row * 3 + 1];
            const float r2 = pz - pos[row * 3 + 2];
            const float dist = sqrtf(r0 * r0 + r1 * r1 + r2 * r2);
            float t = fminf(dist * (512.0f / 6.0f), 511.0f);
            int si = rfl((int)t);
            float fr = t - (float)si;
            float2 tp = *(const float2*)(T2 + (si << 7) + (lane << 1));
            float rbfw = tp.x + fr * (tp.y - tp.x);
            float ss = silu_f(pc0 + ulo(d0));
            float tt = tanh_f(pc1 + uhi(d0));
            float vs = silu_f(pc2 + ulo(d1) + rbfw);
            ws += nrm;
            a1 += nrm * ss;
            a2 += nrm * vs;
            float nt = nrm * tt;
            b30 += nt * r0; b31 += nt * r1; b32 += nt * r2;
            bv0 += nrm * uhi(d1);
            bv1 += nrm * ulo(d2);
            bv2 += nrm * uhi(d2);
        }
        Xs[(size_t)col * 128 + lane] = f2bf(a1);
        Xs[(size_t)col * 128 + 64 + lane] = f2bf(a2);
        const size_t xb = (size_t)col * 576;
        Xv[xb + lane]       = f2bf(b30);
        Xv[xb + 64 + lane]  = f2bf(bv0);
        Xv[xb + 128 + lane] = f2bf(ws * wc0);
        Xv[xb + 192 + lane] = f2bf(b31);
        Xv[xb + 256 + lane] = f2bf(bv1);
        Xv[xb + 320 + lane] = f2bf(ws * wc1);
        Xv[xb + 384 + lane] = f2bf(b32);
        Xv[xb + 448 + lane] = f2bf(bv2);
        Xv[xb + 512 + lane] = f2bf(ws * wc2);
        if (lane == 0) Wsum[col] = ws;
    }
}

// ---------------- fused finalize GEMMs (unchanged from round 6) ------------
__global__ __launch_bounds__(256) void gemm_sv_k(
    const unsigned short* __restrict__ Xs, const unsigned short* __restrict__ BTs,
    const unsigned short* __restrict__ Xv, const unsigned short* __restrict__ BTv,
    const float* __restrict__ bsl, const float* __restrict__ Wsum,
    const float* __restrict__ scalar, const float* __restrict__ vec,
    float* __restrict__ outs, float* __restrict__ outv, int N) {
    const int y = blockIdx.y;
    const int lane = threadIdx.x & 63;
    const int quad = lane >> 4, l = lane & 15;
    const int wave = threadIdx.x >> 6;
    if (y == 0) {
        const int r0 = (blockIdx.x * 4 + wave) * 16;
        if (r0 >= N) return;
        const int arow = min(r0 + l, N - 1);
        const unsigned short* aptr = Xs + (size_t)arow * 128 + quad * 8;
        bf16x8 a[4];
#pragma unroll
        for (int s = 0; s < 4; ++s) a[s] = *(const bf16x8*)(aptr + s * 32);
        const unsigned short* bptr = BTs + (size_t)l * 128 + quad * 8;
        f32x4 acc[4];
#pragma unroll
        for (int nt = 0; nt < 4; ++nt) {
            acc[nt] = (f32x4){0.f, 0.f, 0.f, 0.f};
#pragma unroll
            for (int s = 0; s < 4; ++s) {
                bf16x8 b = *(const bf16x8*)(bptr + (size_t)nt * 16 * 128 + s * 32);
                acc[nt] = MFMA16(a[s], b, acc[nt]);
            }
        }
#pragma unroll
        for (int nt = 0; nt < 4; ++nt) {
            int col = nt * 16 + l;
            float bc = bsl[col];
#pragma unroll
            for (int i = 0; i < 4; ++i) {
                int row = r0 + quad * 4 + i;
                if (row < N) {
                    float wsn = Wsum[row];
                    outs[(size_t)row * 64 + col] =
                        silu_f(acc[nt][i] + wsn * bc) + scalar[(size_t)row * 64 + col];
                }
            }
        }
    } else {
        const int M = 3 * N;
        const int r0 = ((y - 1) * (N / 16) + blockIdx.x * 4 + wave) * 16;
        if (r0 >= M) return;
        const int arow = min(r0 + l, M - 1);
        const unsigned short* aptr = Xv + (size_t)arow * 192 + quad * 8;
        bf16x8 a[6];
#pragma unroll
        for (int s = 0; s < 6; ++s) a[s] = *(const bf16x8*)(aptr + s * 32);
        const unsigned short* bptr = BTv + (size_t)l * 192 + quad * 8;
        f32x4 acc[4];
#pragma unroll
        for (int nt = 0; nt < 4; ++nt) {
            acc[nt] = (f32x4){0.f, 0.f, 0.f, 0.f};
#pragma unroll
            for (int s = 0; s < 6; ++s) {
                bf16x8 b = *(const bf16x8*)(bptr + (size_t)nt * 16 * 192 + s * 32);
                acc[nt] = MFMA16(a[s], b, acc[nt]);
            }
        }
#pragma unroll
        for (int nt = 0; nt < 4; ++nt) {
            int col = nt * 16 + l;
#pragma unroll
            for (int i = 0; i < 4; ++i) {
                int row = r0 + quad * 4 + i;
                if (row < M)
                    outv[(size_t)row * 64 + col] = acc[nt][i] + vec[(size_t)row * 64 + col];
            }
        }
    }
}

extern "C" void kernel_launch(void* const* d_in, const int* in_sizes, int n_in,
                              void* d_out, int out_size, void* d_ws, size_t ws_size,
                              hipStream_t stream) {
    const float* scalar     = (const float*)d_in[0];
    const float* vector     = (const float*)d_in[1];
    const float* position   = (const float*)d_in[2];
    const int*   edge_index = (const int*)d_in[3];
    const float* edge_attr  = (const float*)d_in[4];
    const float* Ws2s       = (const float*)d_in[5];
    const float* bs2s       = (const float*)d_in[6];
    const float* Wv2s       = (const float*)d_in[7];
    const float* bv2s       = (const float*)d_in[8];
    const float* Wsl        = (const float*)d_in[9];
    const float* bsl        = (const float*)d_in[10];
    const float* Ws2v       = (const float*)d_in[11];
    const float* bs2v       = (const float*)d_in[12];
    const float* Wv2v       = (const float*)d_in[13];
    const float* Wvl        = (const float*)d_in[14];

    const int N = in_sizes[0] / 64;
    const int E = in_sizes[3] / 2;
    const size_t sN = (size_t)N;

    float* W = (float*)d_ws;
    // float-slot layout with lifetime overlays:
    float*          dis  = W;                                // N
    unsigned short* X    = (unsigned short*)(W + sN);        // 128N ush; Xs overlay
    unsigned short* Xs   = X;
    unsigned short* R2   = (unsigned short*)(W + 65 * sN);   // 384N ush [n][64][6]
    unsigned short* PC3  = (unsigned short*)(W + 257 * sN);  // 192N ush [n][64][3]
    unsigned short* Xv   = (unsigned short*)(W + 353 * sN);  // 576N ush
    //   overlays inside Xv region (dead before edge kernel writes Xv):
    unsigned long long* dc = (unsigned long long*)(W + 353 * sN);  // N u64
    int*   offA      = (int*)(W + 355 * sN);                 // N+1
    unsigned short* BT6 = (unsigned short*)(W + 358 * sN);   // 24576 ush
    float* Wsum = W + 641 * sN;                              // N
    int*   offB = (int*)(W + 642 * sN);                      // N+1
    unsigned short* BTs = (unsigned short*)(W + 644 * sN);          // 8192 ush
    unsigned short* BTv = (unsigned short*)(W + 644 * sN + 4096);   // 12288 ush
    float* T2   = W + 644 * sN + 10240;                      // 513*64*2 fl
    int2*  SE   = (int2*)(W + 646 * sN);                     // E int2

    float* outs = (float*)d_out;                             // 64N
    float* outv = outs + 64 * sN;                            // 192N

    PreArgs pa;
    pa.ei = edge_index; pa.attr = edge_attr;
    pa.scalar = scalar; pa.vec = vector;
    pa.Ws2s = Ws2s; pa.Ws2v = Ws2v; pa.Wv2s = Wv2s;
    pa.Wsl = Wsl; pa.Wvl = Wvl; pa.Wv2v = Wv2v;
    pa.bs2s = bs2s; pa.bs2v = bs2v; pa.bv2s = bv2s;
    pa.dc = dc; pa.offA = offA; pa.offB = offB; pa.dis = dis;
    pa.X = X; pa.R2 = R2; pa.BT6 = BT6; pa.BTs = BTs; pa.BTv = BTv;
    pa.T2 = T2; pa.SE = SE; pa.PC3 = PC3;
    pa.N = N; pa.E = E;

    void* params[] = { (void*)&pa };
    hipError_t err = hipLaunchCooperativeKernel((const void*)fused_pre_k,
                                                dim3(512), dim3(256), params, 0, stream);
    if (err != hipSuccess) {
        (void)hipGetLastError();
        phase0_k<<<1024, 256, 0, stream>>>(pa);
        phase1_k<<<1024, 256, 0, stream>>>(pa);
        phase2_k<<<(N + 255) / 256, 256, 0, stream>>>(pa);
        phase3_k<<<1024, 256, 0, stream>>>(pa);
    }

    edge_sorted_k<<<((N + CPW - 1) / CPW + 3) / 4, 256, 0, stream>>>(
        position, dis, PC3, R2, T2, SE, offB, Xs, Xv, Wsum, N);

    const int mtilesN = (N + 15) / 16;
    gemm_sv_k<<<dim3((mtilesN + 3) / 4, 4), 256, 0, stream>>>(
        Xs, BTs, Xv, BTv, bsl, Wsum, scalar, vector, outs, outv, N);
}